// Round 7
// baseline (305.609 us; speedup 1.0000x reference)
//
#include <hip/hip_runtime.h>
#include <math.h>

#define BATCH 16
#define ISZ   1024
#define MSZ   32768
#define DSZ   128
#define TOPK  32
#define EPSV  1e-8f
#define NCHUNK 32              // chunks per batch for partial top-k
#define CHUNK  (MSZ / NCHUNK)  // 1024 rows per chunk
#define CPL    (CHUNK / 64)    // 16 sims per lane
#define NBLOCKS  256
#define NTHREADS 256

typedef float f32x4 __attribute__((ext_vector_type(4)));

// Device-wide sense/epoch barrier. bar[0]=arrival count, bar[1]=epoch.
// Zeroed by a captured hipMemsetAsync before each replay. All 256 blocks
// are co-resident (256 thr, ~9KB LDS, <128 VGPR -> >=2 blocks/CU capacity).
__device__ __forceinline__ void grid_barrier(unsigned* bar, unsigned epoch) {
    __syncthreads();
    if (threadIdx.x == 0) {
        __threadfence();   // release: make this block's writes device-visible
        unsigned prev = __hip_atomic_fetch_add(&bar[0], 1u, __ATOMIC_ACQ_REL,
                                               __HIP_MEMORY_SCOPE_AGENT);
        if (prev == NBLOCKS - 1) {
            __hip_atomic_store(&bar[0], 0u, __ATOMIC_RELAXED, __HIP_MEMORY_SCOPE_AGENT);
            __hip_atomic_store(&bar[1], epoch, __ATOMIC_RELEASE, __HIP_MEMORY_SCOPE_AGENT);
        } else {
            while (__hip_atomic_load(&bar[1], __ATOMIC_ACQUIRE,
                                     __HIP_MEMORY_SCOPE_AGENT) < epoch) {
                __builtin_amdgcn_s_sleep(2);
            }
        }
        __threadfence();   // acquire: invalidate stale lines before reads
    }
    __syncthreads();
}

__global__ __launch_bounds__(NTHREADS)
void fused_kernel(const float* __restrict__ x, const float* __restrict__ memory,
                  const float* __restrict__ Ww, const float* __restrict__ bw,
                  const float* __restrict__ Wr, const float* __restrict__ br,
                  const float* __restrict__ Wo, const float* __restrict__ bo,
                  float* __restrict__ wv, float* __restrict__ rq,
                  float* __restrict__ sim, float* __restrict__ cand_v,
                  int* __restrict__ cand_i, float* __restrict__ u,
                  unsigned* __restrict__ bar,
                  float* __restrict__ out, float* __restrict__ out_nm) {
    __shared__ float qn_s[BATCH];
    __shared__ int   topi[TOPK];
    __shared__ float r_s[DSZ];
    __shared__ float s_sh;
    __shared__ f32x4 u_s[BATCH * DSZ / 4];   // 8 KiB

    const int tid  = threadIdx.x;
    const int bid  = blockIdx.x;
    const int lane = tid & 63;
    const int wid  = tid >> 6;

    // ---------------- Phase 0: projections (wv, rq) --------------------------
    // 4096 dot-tasks (b,d,mat) over 1024 waves, 4 tasks/wave.
    {
        int wg = bid * 4 + wid;                 // 0..1023
        #pragma unroll
        for (int t = 0; t < 4; ++t) {
            int T   = wg * 4 + t;               // 0..4095
            int b   = T >> 8;
            int d   = (T >> 1) & 127;
            int mat = T & 1;
            const float* wrow = (mat ? Wr : Ww) + (size_t)d * ISZ;
            const float* xr   = x + (size_t)b * ISZ;
            float a = 0.f;
            #pragma unroll
            for (int i = 0; i < 16; ++i)
                a = fmaf(xr[lane + 64 * i], wrow[lane + 64 * i], a);
            for (int off = 32; off; off >>= 1) a += __shfl_down(a, off);
            if (lane == 0) {
                if (mat) rq[b * DSZ + d] = a + br[d];
                else     wv[b * DSZ + d] = a + bw[d];
            }
        }
    }
    grid_barrier(bar, 1);

    // ---------------- Phase 1: similarities (+ fused row norm) ---------------
    // thread (tid<128) = one memory row; q loads wave-uniform -> scalar loads.
    if (tid < 128) {
        int b = tid >> 3, seg = tid & 7;
        float a = 0.f;
        #pragma unroll
        for (int j = 0; j < 16; ++j) {
            float v = rq[b * DSZ + seg * 16 + j];
            a = fmaf(v, v, a);
        }
        for (int off = 4; off; off >>= 1) a += __shfl_down(a, off, 8);
        if (seg == 0) qn_s[b] = fmaxf(sqrtf(a), EPSV);
    }
    __syncthreads();
    if (tid < 128) {
        int r = bid * 128 + tid;
        const f32x4* row = (const f32x4*)(memory + (size_t)r * DSZ);
        const f32x4* q4  = (const f32x4*)rq;   // uniform index -> s_load
        float acc[BATCH];
        #pragma unroll
        for (int b = 0; b < BATCH; ++b) acc[b] = 0.f;
        float nrm = 0.f;
        #pragma unroll 4
        for (int j = 0; j < 32; ++j) {
            f32x4 v = row[j];
            nrm = fmaf(v.x, v.x, fmaf(v.y, v.y, fmaf(v.z, v.z, fmaf(v.w, v.w, nrm))));
            #pragma unroll
            for (int b = 0; b < BATCH; ++b) {
                f32x4 q = q4[b * 32 + j];
                acc[b] = fmaf(v.x, q.x, fmaf(v.y, q.y, fmaf(v.z, q.z, fmaf(v.w, q.w, acc[b]))));
            }
        }
        float mnr = fmaxf(sqrtf(nrm), EPSV);
        #pragma unroll
        for (int b = 0; b < BATCH; ++b)
            sim[(size_t)b * MSZ + r] = acc[b] / (qn_s[b] * mnr);
    }
    grid_barrier(bar, 2);

    // ---------------- Phase 2: per-wave partial top-32 -----------------------
    // 512 wave-tasks; waves 0/1 of every block. Exact jax.lax.top_k order.
    if (wid < 2) {
        int task  = bid * 2 + wid;   // 0..511
        int b     = task >> 5;       // NCHUNK = 32
        int chunk = task & 31;
        int base  = chunk * CHUNK;
        const float* s = sim + (size_t)b * MSZ + base;

        float val[CPL];
        #pragma unroll
        for (int i = 0; i < CPL; ++i) val[i] = s[i * 64 + lane];

        float keep_v = -INFINITY; int keep_i = 0x7FFFFFFF;
        for (int k = 0; k < TOPK; ++k) {
            float lv = -INFINITY; int li = 0x7FFFFFFF;
            #pragma unroll
            for (int i = 0; i < CPL; ++i) {
                int gi = base + i * 64 + lane;
                bool better = val[i] > lv;      // ascending gi: '>' keeps smaller idx
                lv = better ? val[i] : lv;
                li = better ? gi : li;
            }
            float bv = lv; int bi = li;
            #pragma unroll
            for (int off = 32; off; off >>= 1) {
                float ov = __shfl_xor(bv, off);
                int   oi = __shfl_xor(bi, off);
                if (ov > bv || (ov == bv && oi < bi)) { bv = ov; bi = oi; }
            }
            if (lane == k) { keep_v = bv; keep_i = bi; }
            #pragma unroll
            for (int i = 0; i < CPL; ++i) {
                int gi = base + i * 64 + lane;
                val[i] = (gi == bi) ? -INFINITY : val[i];
            }
        }
        if (lane < TOPK) {
            cand_v[task * TOPK + lane] = keep_v;
            cand_i[task * TOPK + lane] = keep_i;
        }
    }
    grid_barrier(bar, 3);

    // ---------------- Phase 3: merge -> top-32; retrieved; u; out ------------
    if (bid < BATCH) {
        int b = bid;
        const int NC = NCHUNK * TOPK;   // 1024 candidates
        const int PL = NC / 64;         // 16 per lane
        if (tid < 64) {
            float val[PL]; int idx[PL];
            #pragma unroll
            for (int i = 0; i < PL; ++i) {
                val[i] = cand_v[b * NC + i * 64 + lane];
                idx[i] = cand_i[b * NC + i * 64 + lane];
            }
            for (int k = 0; k < TOPK; ++k) {
                float lv = -INFINITY; int li = 0x7FFFFFFF;
                #pragma unroll
                for (int i = 0; i < PL; ++i) {
                    bool better = (val[i] > lv) || (val[i] == lv && idx[i] < li);
                    lv = better ? val[i] : lv;
                    li = better ? idx[i] : li;
                }
                float bv = lv; int bi = li;
                #pragma unroll
                for (int off = 32; off; off >>= 1) {
                    float ov = __shfl_xor(bv, off);
                    int   oi = __shfl_xor(bi, off);
                    if (ov > bv || (ov == bv && oi < bi)) { bv = ov; bi = oi; }
                }
                if (lane == k) topi[lane] = bi;
                #pragma unroll
                for (int i = 0; i < PL; ++i)
                    val[i] = (idx[i] == bi) ? -INFINITY : val[i];
            }
        }
        __syncthreads();
        if (tid < DSZ) {
            float rsum = 0.f;
            for (int k = 0; k < TOPK; ++k)
                rsum += memory[(size_t)topi[k] * DSZ + tid];
            r_s[tid] = rsum;
        }
        __syncthreads();
        if (tid < 64) {
            float a = wv[b * DSZ + tid] * r_s[tid] + wv[b * DSZ + 64 + tid] * r_s[64 + tid];
            for (int off = 32; off; off >>= 1) a += __shfl_down(a, off);
            if (tid == 0) s_sh = 1.f / (1.f + expf(-a));
        }
        __syncthreads();
        if (tid < DSZ) u[b * DSZ + tid] = s_sh * wv[b * DSZ + tid];

        const f32x4* r4 = (const f32x4*)r_s;
        for (int i = tid; i < ISZ; i += NTHREADS) {
            const f32x4* w4 = (const f32x4*)(Wo + (size_t)i * DSZ);
            float acc = 0.f;
            #pragma unroll 8
            for (int j = 0; j < 32; ++j) {
                f32x4 w = w4[j];
                f32x4 r = r4[j];
                acc = fmaf(w.x, r.x, fmaf(w.y, r.y, fmaf(w.z, r.z, fmaf(w.w, r.w, acc))));
            }
            out[b * ISZ + i] = acc + bo[i];
        }
    }
    grid_barrier(bar, 4);

    // ---------------- Phase 4: new_memory = memory + u[b] --------------------
    {
        const f32x4* u4 = (const f32x4*)u;
        u_s[tid]       = u4[tid];
        u_s[tid + 256] = u4[tid + 256];
        __syncthreads();
        const f32x4* m = (const f32x4*)memory;
        f32x4* o = (f32x4*)out_nm;
        #pragma unroll 2
        for (int it = 0; it < 16; ++it) {
            size_t f = (size_t)bid * 4096 + (size_t)it * 256 + tid;
            f32x4 m4 = m[f];
            int d4 = (int)(f & 31);
            #pragma unroll
            for (int b = 0; b < BATCH; ++b)
                o[(size_t)b * (MSZ * DSZ / 4) + f] = m4 + u_s[b * 32 + d4];
        }
    }
}

extern "C" void kernel_launch(void* const* d_in, const int* in_sizes, int n_in,
                              void* d_out, int out_size, void* d_ws, size_t ws_size,
                              hipStream_t stream) {
    const float* x      = (const float*)d_in[0];
    const float* memory = (const float*)d_in[1];
    const float* Ww     = (const float*)d_in[2];
    const float* bw     = (const float*)d_in[3];
    const float* Wr     = (const float*)d_in[4];
    const float* br     = (const float*)d_in[5];
    const float* Wo     = (const float*)d_in[6];
    const float* bo     = (const float*)d_in[7];

    float* out    = (float*)d_out;            // [16,1024]
    float* out_nm = out + BATCH * ISZ;        // [16,32768,128]

    float*    ws     = (float*)d_ws;
    float*    wv     = ws;                            // 2048
    float*    rq     = wv + BATCH * DSZ;              // 2048
    float*    sim    = rq + BATCH * DSZ;              // 524288
    float*    cand_v = sim + (size_t)BATCH * MSZ;     // 16384
    int*      cand_i = (int*)(cand_v + BATCH * NCHUNK * TOPK);   // 16384
    float*    u      = (float*)(cand_i + BATCH * NCHUNK * TOPK); // 2048
    unsigned* bar    = (unsigned*)(u + BATCH * DSZ);  // 2 uints

    hipMemsetAsync((void*)bar, 0, 2 * sizeof(unsigned), stream);
    fused_kernel<<<NBLOCKS, NTHREADS, 0, stream>>>(
        x, memory, Ww, bw, Wr, br, Wo, bo,
        wv, rq, sim, cand_v, cand_i, u, bar, out, out_nm);
}

// Round 8
// 237.455 us; speedup vs baseline: 1.2870x; 1.2870x over previous
//
#include <hip/hip_runtime.h>
#include <math.h>

#define BATCH 16
#define ISZ   1024
#define MSZ   32768
#define DSZ   128
#define TOPK  32
#define EPSV  1e-8f
#define NCHUNK 32              // chunks per batch for partial top-k
#define CHUNK  (MSZ / NCHUNK)  // 1024 rows per chunk
#define CPL    (CHUNK / 64)    // 16 sims per lane
#define NBLOCKS  256
#define NTHREADS 256

typedef float f32x4 __attribute__((ext_vector_type(4)));

// Device-wide sense/epoch barrier. bar[0]=arrival count, bar[1]=epoch.
// Zeroed by a captured hipMemsetAsync before each replay.
// Spin is RELAXED (no per-poll L2 invalidate storm); one device fence after
// exit provides acquire ordering (fence-based synchronizes-with: producers
// __threadfence + release-RMW before arrival).
__device__ __forceinline__ void grid_barrier(unsigned* bar, unsigned epoch) {
    __syncthreads();
    if (threadIdx.x == 0) {
        __threadfence();   // release: writeback this XCD's dirty L2 lines
        unsigned prev = __hip_atomic_fetch_add(&bar[0], 1u, __ATOMIC_ACQ_REL,
                                               __HIP_MEMORY_SCOPE_AGENT);
        if (prev == NBLOCKS - 1) {
            __hip_atomic_store(&bar[0], 0u, __ATOMIC_RELAXED, __HIP_MEMORY_SCOPE_AGENT);
            __hip_atomic_store(&bar[1], epoch, __ATOMIC_RELEASE, __HIP_MEMORY_SCOPE_AGENT);
        } else {
            while (__hip_atomic_load(&bar[1], __ATOMIC_RELAXED,
                                     __HIP_MEMORY_SCOPE_AGENT) < epoch) {
                __builtin_amdgcn_s_sleep(16);
            }
        }
        __threadfence();   // acquire: invalidate stale L1/L2 before reads
    }
    __syncthreads();
}

__global__ __launch_bounds__(NTHREADS)
void fused_kernel(const float* __restrict__ x, const float* __restrict__ memory,
                  const float* __restrict__ Ww, const float* __restrict__ bw,
                  const float* __restrict__ Wr, const float* __restrict__ br,
                  const float* __restrict__ Wo, const float* __restrict__ bo,
                  float* __restrict__ wv, float* __restrict__ rq,
                  float* __restrict__ sim, float* __restrict__ cand_v,
                  int* __restrict__ cand_i, float* __restrict__ u,
                  unsigned* __restrict__ bar,
                  float* __restrict__ out, float* __restrict__ out_nm) {
    __shared__ float qn_s[BATCH];
    __shared__ int   topi[TOPK];
    __shared__ float r_s[DSZ];
    __shared__ float s_sh;
    __shared__ f32x4 u_s[BATCH * DSZ / 4];   // 8 KiB

    const int tid  = threadIdx.x;
    const int bid  = blockIdx.x;
    const int lane = tid & 63;
    const int wid  = tid >> 6;

    // ---------------- Phase 0: projections (wv, rq) --------------------------
    // 4096 dot-tasks (b,d,mat) over 1024 waves, 4 tasks/wave.
    {
        int wg = bid * 4 + wid;                 // 0..1023
        #pragma unroll
        for (int t = 0; t < 4; ++t) {
            int T   = wg * 4 + t;               // 0..4095
            int b   = T >> 8;
            int d   = (T >> 1) & 127;
            int mat = T & 1;
            const float* wrow = (mat ? Wr : Ww) + (size_t)d * ISZ;
            const float* xr   = x + (size_t)b * ISZ;
            float a = 0.f;
            #pragma unroll
            for (int i = 0; i < 16; ++i)
                a = fmaf(xr[lane + 64 * i], wrow[lane + 64 * i], a);
            for (int off = 32; off; off >>= 1) a += __shfl_down(a, off);
            if (lane == 0) {
                if (mat) rq[b * DSZ + d] = a + br[d];
                else     wv[b * DSZ + d] = a + bw[d];
            }
        }
    }
    grid_barrier(bar, 1);

    // ---------------- Phase 1: similarities (+ fused row norm) ---------------
    // thread (tid<128) = one memory row; 16 fully-unrolled loads in flight
    // (16 KB/wave); q loads wave-uniform -> scalar loads feeding FMA directly.
    if (tid < 128) {
        int b0 = tid >> 3, seg = tid & 7;
        float a = 0.f;
        #pragma unroll
        for (int j = 0; j < 16; ++j) {
            float v = rq[b0 * DSZ + seg * 16 + j];
            a = fmaf(v, v, a);
        }
        for (int off = 4; off; off >>= 1) a += __shfl_down(a, off, 8);
        if (seg == 0) qn_s[b0] = fmaxf(sqrtf(a), EPSV);
    }
    __syncthreads();
    if (tid < 128) {
        int r = bid * 128 + tid;
        const f32x4* rowp = (const f32x4*)(memory + (size_t)r * DSZ);
        const f32x4* q4   = (const f32x4*)rq;   // uniform index -> s_load
        float acc[BATCH];
        #pragma unroll
        for (int b = 0; b < BATCH; ++b) acc[b] = 0.f;
        float nrm = 0.f;
        f32x4 v[16];
        #pragma unroll
        for (int half = 0; half < 2; ++half) {
            #pragma unroll
            for (int j = 0; j < 16; ++j) v[j] = rowp[half * 16 + j];   // batch-issue
            #pragma unroll
            for (int j = 0; j < 16; ++j) {
                f32x4 w = v[j];
                nrm = fmaf(w.x, w.x, fmaf(w.y, w.y, fmaf(w.z, w.z, fmaf(w.w, w.w, nrm))));
                #pragma unroll
                for (int b = 0; b < BATCH; ++b) {
                    f32x4 q = q4[b * 32 + half * 16 + j];
                    acc[b] = fmaf(w.x, q.x, fmaf(w.y, q.y, fmaf(w.z, q.z, fmaf(w.w, q.w, acc[b]))));
                }
            }
        }
        float mnr = fmaxf(sqrtf(nrm), EPSV);
        #pragma unroll
        for (int b = 0; b < BATCH; ++b)
            sim[(size_t)b * MSZ + r] = acc[b] / (qn_s[b] * mnr);
    }
    grid_barrier(bar, 2);

    // ---------------- Phase 2: per-wave partial top-32 -----------------------
    // 512 wave-tasks; waves 0/1 of every block. Exact jax.lax.top_k order.
    if (wid < 2) {
        int task  = bid * 2 + wid;   // 0..511
        int b     = task >> 5;       // NCHUNK = 32
        int chunk = task & 31;
        int base  = chunk * CHUNK;
        const float* s = sim + (size_t)b * MSZ + base;

        float val[CPL];
        #pragma unroll
        for (int i = 0; i < CPL; ++i) val[i] = s[i * 64 + lane];

        float keep_v = -INFINITY; int keep_i = 0x7FFFFFFF;
        for (int k = 0; k < TOPK; ++k) {
            float lv = -INFINITY; int li = 0x7FFFFFFF;
            #pragma unroll
            for (int i = 0; i < CPL; ++i) {
                int gi = base + i * 64 + lane;
                bool better = val[i] > lv;      // ascending gi: '>' keeps smaller idx
                lv = better ? val[i] : lv;
                li = better ? gi : li;
            }
            float bv = lv; int bi = li;
            #pragma unroll
            for (int off = 32; off; off >>= 1) {
                float ov = __shfl_xor(bv, off);
                int   oi = __shfl_xor(bi, off);
                if (ov > bv || (ov == bv && oi < bi)) { bv = ov; bi = oi; }
            }
            if (lane == k) { keep_v = bv; keep_i = bi; }
            #pragma unroll
            for (int i = 0; i < CPL; ++i) {
                int gi = base + i * 64 + lane;
                val[i] = (gi == bi) ? -INFINITY : val[i];
            }
        }
        if (lane < TOPK) {
            cand_v[task * TOPK + lane] = keep_v;
            cand_i[task * TOPK + lane] = keep_i;
        }
    }
    grid_barrier(bar, 3);

    // ---------------- Phase 3: merge -> top-32; retrieved; u; out ------------
    if (bid < BATCH) {
        int b = bid;
        const int NC = NCHUNK * TOPK;   // 1024 candidates
        const int PL = NC / 64;         // 16 per lane
        if (tid < 64) {
            float val[PL]; int idx[PL];
            #pragma unroll
            for (int i = 0; i < PL; ++i) {
                val[i] = cand_v[b * NC + i * 64 + lane];
                idx[i] = cand_i[b * NC + i * 64 + lane];
            }
            for (int k = 0; k < TOPK; ++k) {
                float lv = -INFINITY; int li = 0x7FFFFFFF;
                #pragma unroll
                for (int i = 0; i < PL; ++i) {
                    bool better = (val[i] > lv) || (val[i] == lv && idx[i] < li);
                    lv = better ? val[i] : lv;
                    li = better ? idx[i] : li;
                }
                float bv = lv; int bi = li;
                #pragma unroll
                for (int off = 32; off; off >>= 1) {
                    float ov = __shfl_xor(bv, off);
                    int   oi = __shfl_xor(bi, off);
                    if (ov > bv || (ov == bv && oi < bi)) { bv = ov; bi = oi; }
                }
                if (lane == k) topi[lane] = bi;
                #pragma unroll
                for (int i = 0; i < PL; ++i)
                    val[i] = (idx[i] == bi) ? -INFINITY : val[i];
            }
        }
        __syncthreads();
        if (tid < DSZ) {
            float rsum = 0.f;
            for (int k = 0; k < TOPK; ++k)
                rsum += memory[(size_t)topi[k] * DSZ + tid];
            r_s[tid] = rsum;
        }
        __syncthreads();
        if (tid < 64) {
            float a = wv[b * DSZ + tid] * r_s[tid] + wv[b * DSZ + 64 + tid] * r_s[64 + tid];
            for (int off = 32; off; off >>= 1) a += __shfl_down(a, off);
            if (tid == 0) s_sh = 1.f / (1.f + expf(-a));
        }
        __syncthreads();
        if (tid < DSZ) u[b * DSZ + tid] = s_sh * wv[b * DSZ + tid];

        const f32x4* r4 = (const f32x4*)r_s;
        for (int i = tid; i < ISZ; i += NTHREADS) {
            const f32x4* w4 = (const f32x4*)(Wo + (size_t)i * DSZ);
            float acc = 0.f;
            #pragma unroll 8
            for (int j = 0; j < 32; ++j) {
                f32x4 w = w4[j];
                f32x4 r = r4[j];
                acc = fmaf(w.x, r.x, fmaf(w.y, r.y, fmaf(w.z, r.z, fmaf(w.w, r.w, acc))));
            }
            out[b * ISZ + i] = acc + bo[i];
        }
    }
    grid_barrier(bar, 4);

    // ---------------- Phase 4: new_memory = memory + u[b] --------------------
    // d4 = f & 31 = tid & 31 is CONSTANT per thread -> hoist all 16 u-vectors
    // into registers; prefetch m4 in groups of 4 (4 KB/wave in flight).
    {
        const f32x4* u4g = (const f32x4*)u;
        u_s[tid]       = u4g[tid];
        u_s[tid + 256] = u4g[tid + 256];
        __syncthreads();
        f32x4 ur[BATCH];
        int d4 = tid & 31;
        #pragma unroll
        for (int b = 0; b < BATCH; ++b) ur[b] = u_s[b * 32 + d4];

        const f32x4* m = (const f32x4*)memory;
        f32x4* o = (f32x4*)out_nm;
        #pragma unroll
        for (int g = 0; g < 4; ++g) {
            size_t f0 = (size_t)bid * 4096 + (size_t)g * 1024 + tid;
            f32x4 m4[4];
            #pragma unroll
            for (int it = 0; it < 4; ++it) m4[it] = m[f0 + it * 256];
            #pragma unroll
            for (int it = 0; it < 4; ++it) {
                size_t f = f0 + it * 256;
                #pragma unroll
                for (int b = 0; b < BATCH; ++b)
                    o[(size_t)b * (MSZ * DSZ / 4) + f] = m4[it] + ur[b];
            }
        }
    }
}

extern "C" void kernel_launch(void* const* d_in, const int* in_sizes, int n_in,
                              void* d_out, int out_size, void* d_ws, size_t ws_size,
                              hipStream_t stream) {
    const float* x      = (const float*)d_in[0];
    const float* memory = (const float*)d_in[1];
    const float* Ww     = (const float*)d_in[2];
    const float* bw     = (const float*)d_in[3];
    const float* Wr     = (const float*)d_in[4];
    const float* br     = (const float*)d_in[5];
    const float* Wo     = (const float*)d_in[6];
    const float* bo     = (const float*)d_in[7];

    float* out    = (float*)d_out;            // [16,1024]
    float* out_nm = out + BATCH * ISZ;        // [16,32768,128]

    float*    ws     = (float*)d_ws;
    float*    wv     = ws;                            // 2048
    float*    rq     = wv + BATCH * DSZ;              // 2048
    float*    sim    = rq + BATCH * DSZ;              // 524288
    float*    cand_v = sim + (size_t)BATCH * MSZ;     // 16384
    int*      cand_i = (int*)(cand_v + BATCH * NCHUNK * TOPK);   // 16384
    float*    u      = (float*)(cand_i + BATCH * NCHUNK * TOPK); // 2048
    unsigned* bar    = (unsigned*)(u + BATCH * DSZ);  // 2 uints

    hipMemsetAsync((void*)bar, 0, 2 * sizeof(unsigned), stream);
    fused_kernel<<<NBLOCKS, NTHREADS, 0, stream>>>(
        x, memory, Ww, bw, Wr, br, Wo, bo,
        wv, rq, sim, cand_v, cand_i, u, bar, out, out_nm);
}

// Round 9
// 222.550 us; speedup vs baseline: 1.3732x; 1.0670x over previous
//
#include <hip/hip_runtime.h>
#include <math.h>

#define BATCH 16
#define ISZ   1024
#define MSZ   32768
#define DSZ   128
#define TOPK  32
#define EPSV  1e-8f
#define NCHUNK 32              // chunks per batch for partial top-k
#define CHUNK  (MSZ / NCHUNK)  // 1024 rows per chunk
#define CPL    (CHUNK / 64)    // 16 sims per lane
#define NBLOCKS  256
#define NTHREADS 256

typedef float f32x4 __attribute__((ext_vector_type(4)));

// Device-wide epoch barrier. bar[0]=arrival count, bar[1]=epoch.
// Zeroed by a captured hipMemsetAsync before each replay. Relaxed spin +
// fence-based acquire (producers __threadfence + release-RMW before arrival).
__device__ __forceinline__ void grid_barrier(unsigned* bar, unsigned epoch) {
    __syncthreads();
    if (threadIdx.x == 0) {
        __threadfence();   // release
        unsigned prev = __hip_atomic_fetch_add(&bar[0], 1u, __ATOMIC_ACQ_REL,
                                               __HIP_MEMORY_SCOPE_AGENT);
        if (prev == NBLOCKS - 1) {
            __hip_atomic_store(&bar[0], 0u, __ATOMIC_RELAXED, __HIP_MEMORY_SCOPE_AGENT);
            __hip_atomic_store(&bar[1], epoch, __ATOMIC_RELEASE, __HIP_MEMORY_SCOPE_AGENT);
        } else {
            while (__hip_atomic_load(&bar[1], __ATOMIC_RELAXED,
                                     __HIP_MEMORY_SCOPE_AGENT) < epoch) {
                __builtin_amdgcn_s_sleep(16);
            }
        }
        __threadfence();   // acquire
    }
    __syncthreads();
}

// ---------------- Fused phases 0-3: proj -> sim -> ptopk -> merge/out/u ------
__global__ __launch_bounds__(NTHREADS)
void fused03_kernel(const float* __restrict__ x, const float* __restrict__ memory,
                    const float* __restrict__ Ww, const float* __restrict__ bw,
                    const float* __restrict__ Wr, const float* __restrict__ br,
                    const float* __restrict__ Wo, const float* __restrict__ bo,
                    float* __restrict__ wv, float* __restrict__ rq,
                    float* __restrict__ sim, float* __restrict__ cand_v,
                    int* __restrict__ cand_i, float* __restrict__ u,
                    unsigned* __restrict__ bar, float* __restrict__ out) {
    __shared__ float qn_s[BATCH];
    __shared__ int   topi[TOPK];
    __shared__ float r_s[DSZ];
    __shared__ float s_sh;

    const int tid  = threadIdx.x;
    const int bid  = blockIdx.x;
    const int lane = tid & 63;
    const int wid  = tid >> 6;

    // ---- Phase 0: projections (wv, rq): 4096 dot-tasks over 1024 waves ----
    {
        int wg = bid * 4 + wid;                 // 0..1023
        #pragma unroll
        for (int t = 0; t < 4; ++t) {
            int T   = wg * 4 + t;               // 0..4095
            int b   = T >> 8;
            int d   = (T >> 1) & 127;
            int mat = T & 1;
            const float* wrow = (mat ? Wr : Ww) + (size_t)d * ISZ;
            const float* xr   = x + (size_t)b * ISZ;
            float a = 0.f;
            #pragma unroll
            for (int i = 0; i < 16; ++i)
                a = fmaf(xr[lane + 64 * i], wrow[lane + 64 * i], a);
            for (int off = 32; off; off >>= 1) a += __shfl_down(a, off);
            if (lane == 0) {
                if (mat) rq[b * DSZ + d] = a + br[d];
                else     wv[b * DSZ + d] = a + bw[d];
            }
        }
    }
    grid_barrier(bar, 1);

    // ---- Phase 1: similarities (+ fused row norm), row loads batch-issued ----
    if (tid < 128) {
        int b0 = tid >> 3, seg = tid & 7;
        float a = 0.f;
        #pragma unroll
        for (int j = 0; j < 16; ++j) {
            float v = rq[b0 * DSZ + seg * 16 + j];
            a = fmaf(v, v, a);
        }
        for (int off = 4; off; off >>= 1) a += __shfl_down(a, off, 8);
        if (seg == 0) qn_s[b0] = fmaxf(sqrtf(a), EPSV);
    }
    __syncthreads();
    if (tid < 128) {
        int r = bid * 128 + tid;
        const f32x4* rowp = (const f32x4*)(memory + (size_t)r * DSZ);
        const f32x4* q4   = (const f32x4*)rq;   // uniform index -> s_load
        float acc[BATCH];
        #pragma unroll
        for (int b = 0; b < BATCH; ++b) acc[b] = 0.f;
        float nrm = 0.f;
        f32x4 v[16];
        #pragma unroll
        for (int half = 0; half < 2; ++half) {
            #pragma unroll
            for (int j = 0; j < 16; ++j) v[j] = rowp[half * 16 + j];
            #pragma unroll
            for (int j = 0; j < 16; ++j) {
                f32x4 w = v[j];
                nrm = fmaf(w.x, w.x, fmaf(w.y, w.y, fmaf(w.z, w.z, fmaf(w.w, w.w, nrm))));
                #pragma unroll
                for (int b = 0; b < BATCH; ++b) {
                    f32x4 q = q4[b * 32 + half * 16 + j];
                    acc[b] = fmaf(w.x, q.x, fmaf(w.y, q.y, fmaf(w.z, q.z, fmaf(w.w, q.w, acc[b]))));
                }
            }
        }
        float mnr = fmaxf(sqrtf(nrm), EPSV);
        #pragma unroll
        for (int b = 0; b < BATCH; ++b)
            sim[(size_t)b * MSZ + r] = acc[b] / (qn_s[b] * mnr);
    }
    grid_barrier(bar, 2);

    // ---- Phase 2: per-wave partial top-32 (waves 0/1), exact top_k order ----
    if (wid < 2) {
        int task  = bid * 2 + wid;   // 0..511
        int b     = task >> 5;       // NCHUNK = 32
        int chunk = task & 31;
        int base  = chunk * CHUNK;
        const float* s = sim + (size_t)b * MSZ + base;

        float val[CPL];
        #pragma unroll
        for (int i = 0; i < CPL; ++i) val[i] = s[i * 64 + lane];

        float keep_v = -INFINITY; int keep_i = 0x7FFFFFFF;
        for (int k = 0; k < TOPK; ++k) {
            float lv = -INFINITY; int li = 0x7FFFFFFF;
            #pragma unroll
            for (int i = 0; i < CPL; ++i) {
                int gi = base + i * 64 + lane;
                bool better = val[i] > lv;      // ascending gi: '>' keeps smaller idx
                lv = better ? val[i] : lv;
                li = better ? gi : li;
            }
            float bv = lv; int bi = li;
            #pragma unroll
            for (int off = 32; off; off >>= 1) {
                float ov = __shfl_xor(bv, off);
                int   oi = __shfl_xor(bi, off);
                if (ov > bv || (ov == bv && oi < bi)) { bv = ov; bi = oi; }
            }
            if (lane == k) { keep_v = bv; keep_i = bi; }
            #pragma unroll
            for (int i = 0; i < CPL; ++i) {
                int gi = base + i * 64 + lane;
                val[i] = (gi == bi) ? -INFINITY : val[i];
            }
        }
        if (lane < TOPK) {
            cand_v[task * TOPK + lane] = keep_v;
            cand_i[task * TOPK + lane] = keep_i;
        }
    }
    grid_barrier(bar, 3);

    // ---- Phase 3: merge -> exact top-32; retrieved; u; out (16 blocks) ----
    if (bid < BATCH) {
        int b = bid;
        const int NC = NCHUNK * TOPK;   // 1024 candidates
        const int PL = NC / 64;         // 16 per lane
        if (tid < 64) {
            float val[PL]; int idx[PL];
            #pragma unroll
            for (int i = 0; i < PL; ++i) {
                val[i] = cand_v[b * NC + i * 64 + lane];
                idx[i] = cand_i[b * NC + i * 64 + lane];
            }
            for (int k = 0; k < TOPK; ++k) {
                float lv = -INFINITY; int li = 0x7FFFFFFF;
                #pragma unroll
                for (int i = 0; i < PL; ++i) {
                    bool better = (val[i] > lv) || (val[i] == lv && idx[i] < li);
                    lv = better ? val[i] : lv;
                    li = better ? idx[i] : li;
                }
                float bv = lv; int bi = li;
                #pragma unroll
                for (int off = 32; off; off >>= 1) {
                    float ov = __shfl_xor(bv, off);
                    int   oi = __shfl_xor(bi, off);
                    if (ov > bv || (ov == bv && oi < bi)) { bv = ov; bi = oi; }
                }
                if (lane == k) topi[lane] = bi;
                #pragma unroll
                for (int i = 0; i < PL; ++i)
                    val[i] = (idx[i] == bi) ? -INFINITY : val[i];
            }
        }
        __syncthreads();
        if (tid < DSZ) {
            float rsum = 0.f;
            for (int k = 0; k < TOPK; ++k)
                rsum += memory[(size_t)topi[k] * DSZ + tid];
            r_s[tid] = rsum;
        }
        __syncthreads();
        if (tid < 64) {
            float a = wv[b * DSZ + tid] * r_s[tid] + wv[b * DSZ + 64 + tid] * r_s[64 + tid];
            for (int off = 32; off; off >>= 1) a += __shfl_down(a, off);
            if (tid == 0) s_sh = 1.f / (1.f + expf(-a));
        }
        __syncthreads();
        if (tid < DSZ) u[b * DSZ + tid] = s_sh * wv[b * DSZ + tid];

        const f32x4* r4 = (const f32x4*)r_s;
        for (int i = tid; i < ISZ; i += NTHREADS) {
            const f32x4* w4 = (const f32x4*)(Wo + (size_t)i * DSZ);
            float acc = 0.f;
            #pragma unroll 8
            for (int j = 0; j < 32; ++j) {
                f32x4 w = w4[j];
                f32x4 r = r4[j];
                acc = fmaf(w.x, r.x, fmaf(w.y, r.y, fmaf(w.z, r.z, fmaf(w.w, r.w, acc))));
            }
            out[b * ISZ + i] = acc + bo[i];
        }
    }
}

// ---------------- bcast: new_memory = memory + u[b] (R1 structure) -----------
// 4096 blocks x 256 threads; 1 float4 of memory per thread, 16 stores.
__global__ void bcast_kernel(const float* __restrict__ memory, const float* __restrict__ u,
                             float* __restrict__ out_nm) {
    __shared__ f32x4 u_s[BATCH * DSZ / 4];   // 8 KiB
    int tid = threadIdx.x;
    const f32x4* u4 = (const f32x4*)u;
    for (int i = tid; i < BATCH * DSZ / 4; i += 256) u_s[i] = u4[i];
    __syncthreads();
    size_t f = (size_t)blockIdx.x * 256 + tid;          // float4 index into memory
    f32x4 m4 = ((const f32x4*)memory)[f];
    int d4 = (int)(f & 31);                              // float4 column within row
    f32x4* o = (f32x4*)out_nm;
    #pragma unroll
    for (int b = 0; b < BATCH; ++b)
        o[(size_t)b * (MSZ * DSZ / 4) + f] = m4 + u_s[b * 32 + d4];
}

extern "C" void kernel_launch(void* const* d_in, const int* in_sizes, int n_in,
                              void* d_out, int out_size, void* d_ws, size_t ws_size,
                              hipStream_t stream) {
    const float* x      = (const float*)d_in[0];
    const float* memory = (const float*)d_in[1];
    const float* Ww     = (const float*)d_in[2];
    const float* bw     = (const float*)d_in[3];
    const float* Wr     = (const float*)d_in[4];
    const float* br     = (const float*)d_in[5];
    const float* Wo     = (const float*)d_in[6];
    const float* bo     = (const float*)d_in[7];

    float* out    = (float*)d_out;            // [16,1024]
    float* out_nm = out + BATCH * ISZ;        // [16,32768,128]

    float*    ws     = (float*)d_ws;
    float*    wv     = ws;                            // 2048
    float*    rq     = wv + BATCH * DSZ;              // 2048
    float*    sim    = rq + BATCH * DSZ;              // 524288
    float*    cand_v = sim + (size_t)BATCH * MSZ;     // 16384
    int*      cand_i = (int*)(cand_v + BATCH * NCHUNK * TOPK);   // 16384
    float*    u      = (float*)(cand_i + BATCH * NCHUNK * TOPK); // 2048
    unsigned* bar    = (unsigned*)(u + BATCH * DSZ);  // 2 uints

    hipMemsetAsync((void*)bar, 0, 2 * sizeof(unsigned), stream);
    fused03_kernel<<<NBLOCKS, NTHREADS, 0, stream>>>(
        x, memory, Ww, bw, Wr, br, Wo, bo,
        wv, rq, sim, cand_v, cand_i, u, bar, out);
    bcast_kernel<<<MSZ * DSZ / 4 / 256, 256, 0, stream>>>(memory, u, out_nm);
}